// Round 1
// baseline (474.202 us; speedup 1.0000x reference)
//
#include <hip/hip_runtime.h>
#include <math.h>

// Problem constants
#define K_KP 15
#define DZB  64
#define HH   192
#define WW   192
#define CH   79                    // K_KP + DZB
#define BATCH 32
#define HWPIX (HH*WW)              // 36864
#define GROUPS_PER_BATCH (HWPIX/4) // 9216 (group = 4 consecutive pixels = 79 float4s)
#define NGROUPS (BATCH*GROUPS_PER_BATCH) // 294912
#define BLKA 256
#define NBLKA (NGROUPS/BLKA)       // 1152
#define BLOCKS_PER_BATCH (GROUPS_PER_BATCH/BLKA) // 36

// ---------------------------------------------------------------------------
// Kernel A: xy-branch softmax statistics.
// Each thread owns one 4-pixel group (one row => fixed h). Reads ONLY the 18
// aligned float4s that cover channels 0..14 of its 4 pixels (60B of every
// 316B record; z-channels never touched). Accumulates per-channel
// {S=sum e, W=sum e*wx, W2=sum e*wx^2}; folds with hx into {S, hx*S, W,
// hx^2*S+W2} and block-reduces 60 values deterministically via LDS.
// ---------------------------------------------------------------------------
__global__ __launch_bounds__(BLKA) void kA(const float* __restrict__ feat,
                                           float* __restrict__ partials) {
  const int tid = threadIdx.x;
  const int g   = blockIdx.x * BLKA + tid;          // group id, < NGROUPS
  const int gg  = g % GROUPS_PER_BATCH;
  const int row = gg / 48;                          // 48 groups per image row
  const int w0  = (gg - row * 48) * 4;
  const float hx = (float)row * 0.01f;

  const float4* __restrict__ F = (const float4*)feat;
  const size_t base = (size_t)g * 79;               // group = exactly 79 float4s

  float aS[15], aW[15], aW2[15];
#pragma unroll
  for (int i = 0; i < 15; i++) { aS[i] = 0.f; aW[i] = 0.f; aW2[i] = 0.f; }

  // 18 aligned float4 loads covering ch0..14 of pixels 0..3
  float4 v0=F[base+0],  v1=F[base+1],  v2=F[base+2],  v3=F[base+3];
  float4 u0=F[base+19], u1=F[base+20], u2=F[base+21], u3=F[base+22], u4=F[base+23];
  float4 x0=F[base+39], x1=F[base+40], x2=F[base+41], x3=F[base+42], x4=F[base+43];
  float4 y0=F[base+59], y1=F[base+60], y2=F[base+61], y3=F[base+62];

  float wx, e, t;
#define ACC(c, val) { e = __expf(val); aS[c] += e; t = e * wx; aW[c] += t; aW2[c] += t * wx; }
  // pixel 0: floats 0..14
  wx = (float)w0 * 0.01f;
  ACC(0,v0.x) ACC(1,v0.y) ACC(2,v0.z) ACC(3,v0.w)
  ACC(4,v1.x) ACC(5,v1.y) ACC(6,v1.z) ACC(7,v1.w)
  ACC(8,v2.x) ACC(9,v2.y) ACC(10,v2.z) ACC(11,v2.w)
  ACC(12,v3.x) ACC(13,v3.y) ACC(14,v3.z)
  // pixel 1: floats 79..93
  wx = (float)(w0+1) * 0.01f;
  ACC(0,u0.w)
  ACC(1,u1.x) ACC(2,u1.y) ACC(3,u1.z) ACC(4,u1.w)
  ACC(5,u2.x) ACC(6,u2.y) ACC(7,u2.z) ACC(8,u2.w)
  ACC(9,u3.x) ACC(10,u3.y) ACC(11,u3.z) ACC(12,u3.w)
  ACC(13,u4.x) ACC(14,u4.y)
  // pixel 2: floats 158..172
  wx = (float)(w0+2) * 0.01f;
  ACC(0,x0.z) ACC(1,x0.w)
  ACC(2,x1.x) ACC(3,x1.y) ACC(4,x1.z) ACC(5,x1.w)
  ACC(6,x2.x) ACC(7,x2.y) ACC(8,x2.z) ACC(9,x2.w)
  ACC(10,x3.x) ACC(11,x3.y) ACC(12,x3.z) ACC(13,x3.w)
  ACC(14,x4.x)
  // pixel 3: floats 237..251
  wx = (float)(w0+3) * 0.01f;
  ACC(0,y0.y) ACC(1,y0.z) ACC(2,y0.w)
  ACC(3,y1.x) ACC(4,y1.y) ACC(5,y1.z) ACC(6,y1.w)
  ACC(7,y2.x) ACC(8,y2.y) ACC(9,y2.z) ACC(10,y2.w)
  ACC(11,y3.x) ACC(12,y3.y) ACC(13,y3.z) ACC(14,y3.w)
#undef ACC

  const float hx2 = hx * hx;

  __shared__ float red[30][BLKA + 1];
  __shared__ float red2[30][8];

#pragma unroll
  for (int chunk = 0; chunk < 2; ++chunk) {
    __syncthreads();
#pragma unroll
    for (int j = 0; j < 30; j++) {
      const int J = chunk * 30 + j;        // stat index = k*4 + s (compile-time)
      const int k = J >> 2, s = J & 3;
      float v = (s == 0) ? aS[k]
              : (s == 1) ? hx * aS[k]
              : (s == 2) ? aW[k]
                         : fmaf(hx2, aS[k], aW2[k]);
      red[j][tid] = v;
    }
    __syncthreads();
    if (tid < 240) {
      const int r = tid >> 3, sg = tid & 7;
      float a = 0.f;
#pragma unroll
      for (int i = 0; i < 32; i++) a += red[r][sg * 32 + i];
      red2[r][sg] = a;
    }
    __syncthreads();
    if (tid < 30) {
      float a = 0.f;
#pragma unroll
      for (int i = 0; i < 8; i++) a += red2[tid][i];
      partials[blockIdx.x * 60 + chunk * 30 + tid] = a;
    }
  }
}

// ---------------------------------------------------------------------------
// Kernel B: single block. Final reduce of partials -> loss_xy; z-branch at the
// 480 gt pixels only (softmax over 64 contiguous channels); scatter-duplicate
// "last update wins" emulation; hard-keypoint reweighting; scalar output.
// ---------------------------------------------------------------------------
__global__ __launch_bounds__(512) void kB(const float* __restrict__ partials,
                                          const float* __restrict__ gt,
                                          const float* __restrict__ feat,
                                          float* __restrict__ out) {
  const int tid = threadIdx.x;
  __shared__ float Lxy[480], Lz[480], sGtz[480];
  __shared__ int   sPix[480];
  __shared__ float lbx[15], lbz[15];

  const int b = tid / 15;
  const int k = tid - b * 15;

  float locz = 0.f, varz = 0.f;
  if (tid < 480) {
    // ---- reduce xy stats over the 36 blocks of batch b ----
    float S = 0.f, Sh = 0.f, Sw = 0.f, Sr = 0.f;
    for (int j = 0; j < BLOCKS_PER_BATCH; ++j) {
      const float* p = partials + ((size_t)(b * BLOCKS_PER_BATCH + j) * 60 + k * 4);
      S += p[0]; Sh += p[1]; Sw += p[2]; Sr += p[3];
    }
    const float lx = Sh / S, ly = Sw / S;
    const float var = Sr / S - (lx * lx + ly * ly);

    const float maxloc = 191.0f * 0.01f;   // (H-1)*LD_XY in f32, as XLA folds it
    const float gtx = fminf(gt[(b * 15 + k) * 3 + 0], maxloc);
    const float gty = fminf(gt[(b * 15 + k) * 3 + 1], maxloc);
    const float gtz = fminf(gt[(b * 15 + k) * 3 + 2], 6.3f); // 0.1*63 -> f32 6.3f

    const float dx = lx - gtx, dy = ly - gty;
    Lxy[tid] = dx * dx + dy * dy + var;

    int ix = (int)rintf(gtx / 0.01f); ix = min(max(ix, 0), HH - 1);
    int iy = (int)rintf(gty / 0.01f); iy = min(max(iy, 0), WW - 1);
    sPix[tid] = ix * WW + iy;
    sGtz[tid] = gtz;

    // ---- z softmax at (b, ix, iy): channels 15..78 ----
    const float* fz = feat + (size_t)(b * HWPIX + ix * WW + iy) * CH + K_KP;
    float Sz = 0.f, S1 = 0.f, S2 = 0.f;
#pragma unroll
    for (int c = 0; c < DZB; ++c) {
      const float ez = __expf(fz[c]);
      const float lz = (float)c * 0.1f;
      Sz += ez;
      S1 += ez * lz;
      S2 += ez * lz * lz;
    }
    locz = S1 / Sz;
    varz = S2 / Sz - locz * locz;
  }
  __syncthreads();
  if (tid < 480) {
    // scatter-set duplicate semantics: later keypoint (larger k) wins
    const int pix = sPix[tid];
    float ge = sGtz[tid];
    for (int k2 = k + 1; k2 < 15; ++k2)
      if (sPix[b * 15 + k2] == pix) ge = sGtz[b * 15 + k2];
    const float d = locz - ge;
    Lz[tid] = d * d + varz;
  }
  __syncthreads();
  if (tid < 15) {
    float a = 0.f, c = 0.f;
    for (int b2 = 0; b2 < BATCH; ++b2) {
      a += Lxy[b2 * 15 + tid];
      c += Lz[b2 * 15 + tid];
    }
    lbx[tid] = a; lbz[tid] = c;
  }
  __syncthreads();
  if (tid == 0) {
    float sx = 0.f, sz = 0.f;
    for (int k2 = 0; k2 < 15; ++k2) { sx += lbx[k2]; sz += lbz[k2]; }
    sx = (sx + 0.001f) / 15.f;
    sz = (sz + 0.001f) / 15.f;
    float L = 0.f;
    for (int k2 = 0; k2 < 15; ++k2)
      L += lbx[k2] * (lbx[k2] / sx) + lbz[k2] * (lbz[k2] / sz);
    out[0] = L;
  }
}

extern "C" void kernel_launch(void* const* d_in, const int* in_sizes, int n_in,
                              void* d_out, int out_size, void* d_ws, size_t ws_size,
                              hipStream_t stream) {
  const float* feat = (const float*)d_in[0];   // [32,192,192,79] f32
  const float* gt   = (const float*)d_in[1];   // [32,15,3] f32
  float* out        = (float*)d_out;           // scalar f32
  float* partials   = (float*)d_ws;            // NBLKA*60 floats = 276,480 B

  hipLaunchKernelGGL(kA, dim3(NBLKA), dim3(BLKA), 0, stream, feat, partials);
  hipLaunchKernelGGL(kB, dim3(1), dim3(512), 0, stream, partials, gt, feat, out);
}